// Round 2
// baseline (496.998 us; speedup 1.0000x reference)
//
#include <hip/hip_runtime.h>

#define NN 100000
#define EE 1600000
#define GG 1000
#define PERG 100
#define KK 30
#define HH 64

#define NB 782      // buckets of 128 nodes: 782*128 = 100096 >= NN
#define CAP 4096    // max edges/bucket (mean 2048, sigma ~45 -> huge margin)
#define CHB 4096    // edges per bucket block -> 391 bucket blocks
#define BUCKET_BLOCKS ((EE + CHB - 1) / CHB)  // 391
#define PROJ_BLOCKS ((NN + 127) / 128)        // 782

// ---- bucket body: LDS histogram + per-(block,bucket) run reservation ----
__device__ __forceinline__ void bucket_body(int bid, float* smem,
                                            const int* __restrict__ src,
                                            const int* __restrict__ dst,
                                            int* __restrict__ gcur,
                                            int* __restrict__ pairs) {
  int* lhist = (int*)smem;
  int* lbase = lhist + NB;
  int* lcur = lbase + NB;
  const int t = threadIdx.x;
  const int c0 = bid * CHB;
  const int c1 = min(c0 + CHB, EE);
  for (int b = t; b < NB; b += 256) {
    lhist[b] = 0;
    lcur[b] = 0;
  }
  __syncthreads();
  for (int e = c0 + t; e < c1; e += 256) atomicAdd(&lhist[dst[e] >> 7], 1);
  __syncthreads();
  for (int b = t; b < NB; b += 256) {
    int c = lhist[b];
    lbase[b] = c ? atomicAdd(&gcur[b], c) : 0;
  }
  __syncthreads();
  for (int e = c0 + t; e < c1; e += 256) {
    int d = dst[e];
    int b = d >> 7;
    int p = atomicAdd(&lcur[b], 1);
    pairs[b * CAP + lbase[b] + p] = (src[e] << 7) | (d & 127);
  }
}

// ---- proj body: X [NN,K] @ (WL|WR) -> P, R. BM=128, 8x8 reg tile ----
template <int K>
__device__ __forceinline__ void proj_body(int bid, float* smem,
                                          const float* __restrict__ X,
                                          const float* __restrict__ WL,
                                          const float* __restrict__ WR,
                                          float* __restrict__ P,
                                          float* __restrict__ R) {
  constexpr int BM = 128, BK = 32, XSP = 40, WSP = 144;
  float* xs = smem;             // 128*40 floats
  float* ws = smem + BM * XSP;  // 32*144 floats
  const int t = threadIdx.x;
  const int row0 = bid * BM;
  const int tc = t & 15, tr = t >> 4;
  const int wcol = tc * 8 + (tc >> 2) * 4;

  float acc[8][8];
#pragma unroll
  for (int i = 0; i < 8; ++i)
#pragma unroll
    for (int j = 0; j < 8; ++j) acc[i][j] = 0.f;

  for (int k0 = 0; k0 < K; k0 += BK) {
    __syncthreads();
    for (int idx = t; idx < BM * 8; idx += 256) {
      int r = idx >> 3, c = idx & 7;
      int row = row0 + r;
      float4 v = make_float4(0.f, 0.f, 0.f, 0.f);
      if (row < NN) v = *reinterpret_cast<const float4*>(&X[(size_t)row * K + k0 + c * 4]);
      *reinterpret_cast<float4*>(&xs[r * XSP + c * 4]) = v;
    }
    for (int idx = t; idx < BK * 16; idx += 256) {
      int kr = idx >> 4, c4 = idx & 15;
      int gcl = c4 >> 1;
      int off = gcl * 8 + (gcl >> 2) * 4 + (c4 & 1) * 4;
      *reinterpret_cast<float4*>(&ws[kr * WSP + off]) =
          *reinterpret_cast<const float4*>(&WL[(k0 + kr) * 64 + c4 * 4]);
      int g2 = gcl + 8;
      int off2 = g2 * 8 + (g2 >> 2) * 4 + (c4 & 1) * 4;
      *reinterpret_cast<float4*>(&ws[kr * WSP + off2]) =
          *reinterpret_cast<const float4*>(&WR[(k0 + kr) * 64 + c4 * 4]);
    }
    __syncthreads();
    for (int kk4 = 0; kk4 < BK; kk4 += 4) {
      float4 a[8];
#pragma unroll
      for (int i = 0; i < 8; ++i)
        a[i] = *reinterpret_cast<const float4*>(&xs[(tr + 16 * i) * XSP + kk4]);
#pragma unroll
      for (int kk = 0; kk < 4; ++kk) {
        float4 b0 = *reinterpret_cast<const float4*>(&ws[(kk4 + kk) * WSP + wcol]);
        float4 b1 = *reinterpret_cast<const float4*>(&ws[(kk4 + kk) * WSP + wcol + 4]);
        float bv[8] = {b0.x, b0.y, b0.z, b0.w, b1.x, b1.y, b1.z, b1.w};
#pragma unroll
        for (int i = 0; i < 8; ++i) {
          float av = (kk == 0) ? a[i].x : (kk == 1) ? a[i].y : (kk == 2) ? a[i].z : a[i].w;
#pragma unroll
          for (int j = 0; j < 8; ++j) acc[i][j] = fmaf(av, bv[j], acc[i][j]);
        }
      }
    }
  }

  float* OUT = (tc < 8) ? P : R;
  int cb = (tc & 7) * 8;
#pragma unroll
  for (int i = 0; i < 8; ++i) {
    int row = row0 + tr + 16 * i;
    if (row < NN) {
      *reinterpret_cast<float4*>(&OUT[(size_t)row * 64 + cb]) =
          make_float4(acc[i][0], acc[i][1], acc[i][2], acc[i][3]);
      *reinterpret_cast<float4*>(&OUT[(size_t)row * 64 + cb + 4]) =
          make_float4(acc[i][4], acc[i][5], acc[i][6], acc[i][7]);
    }
  }
}

// Heterogeneous launch. PROJ BLOCKS FIRST: all 782 long proj blocks become
// resident immediately (<= 1024-block capacity at 4 blocks/CU); the 391 short
// bucket blocks churn through the remaining ~242 slots under proj's shadow.
// (Previous order put 149 proj blocks in a straggler tail -> 21% occupancy.)
__global__ __launch_bounds__(256) void fused_bucket_proj(const int* __restrict__ src,
                                                         const int* __restrict__ dst,
                                                         int* __restrict__ gcur,
                                                         int* __restrict__ pairs,
                                                         const float* __restrict__ X,
                                                         const float* __restrict__ WL,
                                                         const float* __restrict__ WR,
                                                         float* __restrict__ P,
                                                         float* __restrict__ R) {
  __shared__ float smem[128 * 40 + 32 * 144];  // 38912 B, covers both roles
  if (blockIdx.x < PROJ_BLOCKS)
    proj_body<128>(blockIdx.x, smem, X, WL, WR, P, R);
  else
    bucket_body(blockIdx.x - PROJ_BLOCKS, smem, src, dst, gcur, pairs);
}

template <int K>
__global__ __launch_bounds__(256) void proj_kernel(const float* __restrict__ X,
                                                   const float* __restrict__ WL,
                                                   const float* __restrict__ WR,
                                                   float* __restrict__ P,
                                                   float* __restrict__ R) {
  __shared__ float smem[128 * 40 + 32 * 144];
  proj_body<K>(blockIdx.x, smem, X, WL, WR, P, R);
}

// Phase C with inline scan: block b computes base = sum(gcur[0..b)) itself
// (<=782 L2-cached ints), then 128-bin LDS counting sort -> row_start/cnt/eidx.
__global__ __launch_bounds__(256) void csr_kernel(const int* __restrict__ gcur,
                                                  const int* __restrict__ pairs,
                                                  int* __restrict__ row_start,
                                                  int* __restrict__ cnt,
                                                  int* __restrict__ eidx) {
  __shared__ int vals[CAP];
  __shared__ int hist[128];
  __shared__ int offs[128];
  __shared__ int cur[128];
  __shared__ int red[4];
  const int b = blockIdx.x;
  const int t = threadIdx.x;
  // inline exclusive prefix over bucket counts
  int s = 0;
  for (int i = t; i < b; i += 256) s += gcur[i];
#pragma unroll
  for (int off = 32; off > 0; off >>= 1) s += __shfl_xor(s, off);
  if ((t & 63) == 0) red[t >> 6] = s;
  if (t < 128) {
    hist[t] = 0;
    cur[t] = 0;
  }
  __syncthreads();
  const int base = red[0] + red[1] + red[2] + red[3];
  const int nb = gcur[b];
  for (int i = t; i < nb; i += 256) {
    int v = pairs[b * CAP + i];
    vals[i] = v;
    atomicAdd(&hist[v & 127], 1);
  }
  __syncthreads();
  if (t < 128) {
    int ss = 0;
    for (int m = 0; m < t; ++m) ss += hist[m];
    offs[t] = ss;
    int node = b * 128 + t;
    if (node < NN) {
      row_start[node] = base + ss;
      cnt[node] = hist[t];
    }
  }
  __syncthreads();
  for (int i = t; i < nb; i += 256) {
    int v = vals[i];
    int ld = v & 127;
    int p = atomicAdd(&cur[ld], 1);
    eidx[base + offs[ld] + p] = v >> 7;
  }
}

// agg v2: quarter (16 lanes) per node, lane = fixed feature-quarter (4 floats).
// All 16 edge-gathers of a chunk are independent -> up to 16 float4 loads in
// flight per lane (4x the old scheme); cross-lane reduce eliminated entirely
// (features are lane-partitioned); h/R fully coalesced 256B per quarter.
__global__ __launch_bounds__(256) void agg_kernel(const float* __restrict__ P,
                                                  const float* __restrict__ R,
                                                  const float* __restrict__ bias,
                                                  const int* __restrict__ row_start,
                                                  const int* __restrict__ cnt,
                                                  const int* __restrict__ eidx,
                                                  float* __restrict__ h,
                                                  float* __restrict__ keys) {
  const int wv = (blockIdx.x * 256 + threadIdx.x) >> 6;  // wave id
  const int lane = threadIdx.x & 63;
  const int q = lane >> 4;   // node slot within wave
  const int ql = lane & 15;  // feature quarter
  const int node = wv * 4 + q;
  if (node >= NN) return;
  const int base = row_start[node];
  const int deg = cnt[node];
  float4 acc = make_float4(0.f, 0.f, 0.f, 0.f);

  for (int e0 = 0; e0 < deg; e0 += 16) {
    const int rem = deg - e0;
    const int ii = (ql < rem) ? ql : (rem - 1);
    int idx = eidx[base + e0 + ii];  // 16 indices live in the quarter's lanes
#pragma unroll
    for (int j = 0; j < 16; ++j) {
      const int sj = __shfl(idx, (lane & 48) | j);  // broadcast within quarter
      const float wj = (j < rem) ? 1.f : 0.f;
      const float4 vj = *reinterpret_cast<const float4*>(&P[(size_t)sj * 64 + ql * 4]);
      acc.x = fmaf(wj, vj.x, acc.x);
      acc.y = fmaf(wj, vj.y, acc.y);
      acc.z = fmaf(wj, vj.z, acc.z);
      acc.w = fmaf(wj, vj.w, acc.w);
    }
  }

  const float dv = fmaxf((float)deg, 1.0f);
  float4 r4 = *reinterpret_cast<const float4*>(&R[(size_t)node * 64 + ql * 4]);
  float4 b4 = *reinterpret_cast<const float4*>(&bias[ql * 4]);
  float4 o;
  o.x = fmaxf(acc.x / dv + b4.x + r4.x, 0.f);
  o.y = fmaxf(acc.y / dv + b4.y + r4.y, 0.f);
  o.z = fmaxf(acc.z / dv + b4.z + r4.z, 0.f);
  o.w = fmaxf(acc.w / dv + b4.w + r4.w, 0.f);
  *reinterpret_cast<float4*>(&h[(size_t)node * 64 + ql * 4]) = o;
  if (keys != nullptr && ql == 15) keys[node] = o.w;  // feature 63
}

// one block (256 thr) per graph: stable top-30, conv1d, MLP head.
__global__ __launch_bounds__(256) void head_kernel(const float* __restrict__ h,
                                                   const float* __restrict__ keysArr,
                                                   const float* __restrict__ cw,
                                                   const float* __restrict__ cb,
                                                   const float* __restrict__ w1,
                                                   const float* __restrict__ bb1,
                                                   const float* __restrict__ w2,
                                                   const float* __restrict__ bb2,
                                                   float* __restrict__ out) {
  __shared__ float key[PERG];
  __shared__ int sel[KK];
  __shared__ float feat[34 * 65];
  __shared__ float cwT[192 * 33];
  __shared__ float z[896];
  __shared__ float psum[256];
  const int g = blockIdx.x;
  const int t = threadIdx.x;

  for (int idx = t; idx < 32 * 192; idx += 256) {
    int o = idx / 192, k = idx % 192;
    cwT[k * 33 + o] = cw[idx];
  }
  if (t < PERG) key[t] = keysArr[g * PERG + t];
  __syncthreads();

  if (t < PERG) {
    float kv = key[t];
    int r = 0;
    for (int m = 0; m < PERG; ++m) {
      float km = key[m];
      r += (int)((km > kv) || (km == kv && m < t));
    }
    if (r < KK) sel[r] = t;
  }
  __syncthreads();

  for (int idx = t; idx < KK * HH; idx += 256) {
    int r = idx >> 6, f = idx & 63;
    feat[r * 65 + f] = h[(size_t)(g * PERG + sel[r]) * HH + f];
  }
  __syncthreads();

  {
    const int o = t & 31;
    const int pg = t >> 5;
    float zacc[4] = {0.f, 0.f, 0.f, 0.f};
    int i = 0, tt = 0;
    for (int k = 0; k < 192; ++k) {
      float c = cwT[k * 33 + o];
#pragma unroll
      for (int j = 0; j < 4; ++j) {
        int p = pg + 8 * j;
        zacc[j] = fmaf(c, feat[(p + tt) * 65 + i], zacc[j]);
      }
      if (++tt == 3) {
        tt = 0;
        ++i;
      }
    }
    float cbo = cb[o];
#pragma unroll
    for (int j = 0; j < 4; ++j) {
      int p = pg + 8 * j;
      if (p < 28) z[o * 28 + p] = fmaxf(zacc[j] + cbo, 0.f);
    }
  }
  __syncthreads();

  {
    const int hh = t & 63;
    const int quarter = t >> 6;
    const int q0 = quarter * 224;
    float acc = 0.f;
    for (int q = 0; q < 224; ++q)
      acc = fmaf(z[q0 + q], w1[(size_t)(q0 + q) * 64 + hh], acc);
    psum[t] = acc;
  }
  __syncthreads();

  if (t < 64) {
    float o1 = fmaxf(bb1[t] + psum[t] + psum[t + 64] + psum[t + 128] + psum[t + 192], 0.f);
    float v = o1 * w2[t];
#pragma unroll
    for (int off = 32; off > 0; off >>= 1) v += __shfl_down(v, off);
    if (t == 0) out[g] = v + bb2[0];
  }
}

extern "C" void kernel_launch(void* const* d_in, const int* in_sizes, int n_in,
                              void* d_out, int out_size, void* d_ws, size_t ws_size,
                              hipStream_t stream) {
  const float* x = (const float*)d_in[0];
  const int* src = (const int*)d_in[1];
  const int* dst = (const int*)d_in[2];
  const float* wl1 = (const float*)d_in[4];
  const float* wr1 = (const float*)d_in[5];
  const float* b1 = (const float*)d_in[6];
  const float* wl2 = (const float*)d_in[7];
  const float* wr2 = (const float*)d_in[8];
  const float* b2 = (const float*)d_in[9];
  const float* wl3 = (const float*)d_in[10];
  const float* wr3 = (const float*)d_in[11];
  const float* b3 = (const float*)d_in[12];
  const float* cw = (const float*)d_in[13];
  const float* cb = (const float*)d_in[14];
  const float* w1 = (const float*)d_in[15];
  const float* bb1 = (const float*)d_in[16];
  const float* w2 = (const float*)d_in[17];
  const float* bb2 = (const float*)d_in[18];
  float* out = (float*)d_out;

  char* w = (char*)d_ws;
  auto carve = [&](size_t bytes) {
    char* p = w;
    w += (bytes + 255) & ~(size_t)255;
    return p;
  };
  int* row_start = (int*)carve((size_t)NN * 4);
  int* cnt = (int*)carve((size_t)NN * 4);
  int* eidx = (int*)carve((size_t)EE * 4);
  float* P = (float*)carve((size_t)NN * 64 * 4);
  float* R = (float*)carve((size_t)NN * 64 * 4);
  float* hbuf = (float*)carve((size_t)NN * 64 * 4);
  float* keys = (float*)carve((size_t)NN * 4);
  int* gcur = (int*)carve((size_t)NB * 4);
  // pairs aliases hbuf (NOT P: proj1 writes P concurrently with bucket now).
  // csr reads pairs before agg1 writes hbuf (stream order) -> safe.
  int* pairs = (int*)hbuf;  // NB*CAP*4 = 12.8 MB < 25.6 MB

  hipMemsetAsync(gcur, 0, (size_t)NB * 4, stream);
  fused_bucket_proj<<<BUCKET_BLOCKS + PROJ_BLOCKS, 256, 0, stream>>>(
      src, dst, gcur, pairs, x, wl1, wr1, P, R);
  csr_kernel<<<NB, 256, 0, stream>>>(gcur, pairs, row_start, cnt, eidx);

  const int aggGrid = (NN + 15) / 16;  // 4 nodes per wave, 4 waves per block
  agg_kernel<<<aggGrid, 256, 0, stream>>>(P, R, b1, row_start, cnt, eidx, hbuf, nullptr);
  proj_kernel<64><<<PROJ_BLOCKS, 256, 0, stream>>>(hbuf, wl2, wr2, P, R);
  agg_kernel<<<aggGrid, 256, 0, stream>>>(P, R, b2, row_start, cnt, eidx, hbuf, nullptr);
  proj_kernel<64><<<PROJ_BLOCKS, 256, 0, stream>>>(hbuf, wl3, wr3, P, R);
  agg_kernel<<<aggGrid, 256, 0, stream>>>(P, R, b3, row_start, cnt, eidx, hbuf, keys);
  head_kernel<<<GG, 256, 0, stream>>>(hbuf, keys, cw, cb, w1, bb1, w2, bb2, out);
}

// Round 3
// 490.745 us; speedup vs baseline: 1.0127x; 1.0127x over previous
//
#include <hip/hip_runtime.h>

#define NN 100000
#define EE 1600000
#define GG 1000
#define PERG 100
#define KK 30
#define HH 64

#define NB 782      // buckets of 128 nodes: 782*128 = 100096 >= NN
#define CAP 4096    // max edges/bucket (mean 2048, sigma ~45 -> huge margin)
#define CHB 4096    // edges per bucket block -> 391 bucket blocks
#define BUCKET_BLOCKS ((EE + CHB - 1) / CHB)  // 391
#define PROJ_BLOCKS ((NN + 127) / 128)        // 782
#define LAYER_BLOCKS PROJ_BLOCKS

// ---- bucket body: LDS histogram + per-(block,bucket) run reservation ----
__device__ __forceinline__ void bucket_body(int bid, float* smem,
                                            const int* __restrict__ src,
                                            const int* __restrict__ dst,
                                            int* __restrict__ gcur,
                                            int* __restrict__ pairs) {
  int* lhist = (int*)smem;
  int* lbase = lhist + NB;
  int* lcur = lbase + NB;
  const int t = threadIdx.x;
  const int c0 = bid * CHB;
  const int c1 = min(c0 + CHB, EE);
  for (int b = t; b < NB; b += 256) {
    lhist[b] = 0;
    lcur[b] = 0;
  }
  __syncthreads();
  for (int e = c0 + t; e < c1; e += 256) atomicAdd(&lhist[dst[e] >> 7], 1);
  __syncthreads();
  for (int b = t; b < NB; b += 256) {
    int c = lhist[b];
    lbase[b] = c ? atomicAdd(&gcur[b], c) : 0;
  }
  __syncthreads();
  for (int e = c0 + t; e < c1; e += 256) {
    int d = dst[e];
    int b = d >> 7;
    int p = atomicAdd(&lcur[b], 1);
    pairs[b * CAP + lbase[b] + p] = (src[e] << 7) | (d & 127);
  }
}

// ---- proj body: X [NN,K] @ (WL|WR) -> P, R. BM=128, 8x8 reg tile ----
template <int K>
__device__ __forceinline__ void proj_body(int bid, float* smem,
                                          const float* __restrict__ X,
                                          const float* __restrict__ WL,
                                          const float* __restrict__ WR,
                                          float* __restrict__ P,
                                          float* __restrict__ R) {
  constexpr int BM = 128, BK = 32, XSP = 40, WSP = 144;
  float* xs = smem;             // 128*40 floats
  float* ws = smem + BM * XSP;  // 32*144 floats
  const int t = threadIdx.x;
  const int row0 = bid * BM;
  const int tc = t & 15, tr = t >> 4;
  const int wcol = tc * 8 + (tc >> 2) * 4;

  float acc[8][8];
#pragma unroll
  for (int i = 0; i < 8; ++i)
#pragma unroll
    for (int j = 0; j < 8; ++j) acc[i][j] = 0.f;

  for (int k0 = 0; k0 < K; k0 += BK) {
    __syncthreads();
    for (int idx = t; idx < BM * 8; idx += 256) {
      int r = idx >> 3, c = idx & 7;
      int row = row0 + r;
      float4 v = make_float4(0.f, 0.f, 0.f, 0.f);
      if (row < NN) v = *reinterpret_cast<const float4*>(&X[(size_t)row * K + k0 + c * 4]);
      *reinterpret_cast<float4*>(&xs[r * XSP + c * 4]) = v;
    }
    for (int idx = t; idx < BK * 16; idx += 256) {
      int kr = idx >> 4, c4 = idx & 15;
      int gcl = c4 >> 1;
      int off = gcl * 8 + (gcl >> 2) * 4 + (c4 & 1) * 4;
      *reinterpret_cast<float4*>(&ws[kr * WSP + off]) =
          *reinterpret_cast<const float4*>(&WL[(k0 + kr) * 64 + c4 * 4]);
      int g2 = gcl + 8;
      int off2 = g2 * 8 + (g2 >> 2) * 4 + (c4 & 1) * 4;
      *reinterpret_cast<float4*>(&ws[kr * WSP + off2]) =
          *reinterpret_cast<const float4*>(&WR[(k0 + kr) * 64 + c4 * 4]);
    }
    __syncthreads();
    for (int kk4 = 0; kk4 < BK; kk4 += 4) {
      float4 a[8];
#pragma unroll
      for (int i = 0; i < 8; ++i)
        a[i] = *reinterpret_cast<const float4*>(&xs[(tr + 16 * i) * XSP + kk4]);
#pragma unroll
      for (int kk = 0; kk < 4; ++kk) {
        float4 b0 = *reinterpret_cast<const float4*>(&ws[(kk4 + kk) * WSP + wcol]);
        float4 b1 = *reinterpret_cast<const float4*>(&ws[(kk4 + kk) * WSP + wcol + 4]);
        float bv[8] = {b0.x, b0.y, b0.z, b0.w, b1.x, b1.y, b1.z, b1.w};
#pragma unroll
        for (int i = 0; i < 8; ++i) {
          float av = (kk == 0) ? a[i].x : (kk == 1) ? a[i].y : (kk == 2) ? a[i].z : a[i].w;
#pragma unroll
          for (int j = 0; j < 8; ++j) acc[i][j] = fmaf(av, bv[j], acc[i][j]);
        }
      }
    }
  }

  float* OUT = (tc < 8) ? P : R;
  int cb = (tc & 7) * 8;
#pragma unroll
  for (int i = 0; i < 8; ++i) {
    int row = row0 + tr + 16 * i;
    if (row < NN) {
      *reinterpret_cast<float4*>(&OUT[(size_t)row * 64 + cb]) =
          make_float4(acc[i][0], acc[i][1], acc[i][2], acc[i][3]);
      *reinterpret_cast<float4*>(&OUT[(size_t)row * 64 + cb + 4]) =
          make_float4(acc[i][4], acc[i][5], acc[i][6], acc[i][7]);
    }
  }
}

// Heterogeneous launch: proj blocks first (all resident), buckets backfill.
__global__ __launch_bounds__(256) void fused_bucket_proj(const int* __restrict__ src,
                                                         const int* __restrict__ dst,
                                                         int* __restrict__ gcur,
                                                         int* __restrict__ pairs,
                                                         const float* __restrict__ X,
                                                         const float* __restrict__ WL,
                                                         const float* __restrict__ WR,
                                                         float* __restrict__ P,
                                                         float* __restrict__ R) {
  __shared__ float smem[128 * 40 + 32 * 144];  // 38912 B, covers both roles
  if (blockIdx.x < PROJ_BLOCKS)
    proj_body<128>(blockIdx.x, smem, X, WL, WR, P, R);
  else
    bucket_body(blockIdx.x - PROJ_BLOCKS, smem, src, dst, gcur, pairs);
}

template <int K>
__global__ __launch_bounds__(256) void proj_kernel(const float* __restrict__ X,
                                                   const float* __restrict__ WL,
                                                   const float* __restrict__ WR,
                                                   float* __restrict__ P,
                                                   float* __restrict__ R) {
  __shared__ float smem[128 * 40 + 32 * 144];
  proj_body<K>(blockIdx.x, smem, X, WL, WR, P, R);
}

// Phase C with inline scan -> row_start/cnt/eidx (CSR sorted by dst).
__global__ __launch_bounds__(256) void csr_kernel(const int* __restrict__ gcur,
                                                  const int* __restrict__ pairs,
                                                  int* __restrict__ row_start,
                                                  int* __restrict__ cnt,
                                                  int* __restrict__ eidx) {
  __shared__ int vals[CAP];
  __shared__ int hist[128];
  __shared__ int offs[128];
  __shared__ int cur[128];
  __shared__ int red[4];
  const int b = blockIdx.x;
  const int t = threadIdx.x;
  int s = 0;
  for (int i = t; i < b; i += 256) s += gcur[i];
#pragma unroll
  for (int off = 32; off > 0; off >>= 1) s += __shfl_xor(s, off);
  if ((t & 63) == 0) red[t >> 6] = s;
  if (t < 128) {
    hist[t] = 0;
    cur[t] = 0;
  }
  __syncthreads();
  const int base = red[0] + red[1] + red[2] + red[3];
  const int nb = gcur[b];
  for (int i = t; i < nb; i += 256) {
    int v = pairs[b * CAP + i];
    vals[i] = v;
    atomicAdd(&hist[v & 127], 1);
  }
  __syncthreads();
  if (t < 128) {
    int ss = 0;
    for (int m = 0; m < t; ++m) ss += hist[m];
    offs[t] = ss;
    int node = b * 128 + t;
    if (node < NN) {
      row_start[node] = base + ss;
      cnt[node] = hist[t];
    }
  }
  __syncthreads();
  for (int i = t; i < nb; i += 256) {
    int v = vals[i];
    int ld = v & 127;
    int p = atomicAdd(&cur[ld], 1);
    eidx[base + offs[ld] + p] = v >> 7;
  }
}

// agg v2: quarter (16 lanes) per node, lane = fixed feature-quarter (4 floats).
__global__ __launch_bounds__(256) void agg_kernel(const float* __restrict__ P,
                                                  const float* __restrict__ R,
                                                  const float* __restrict__ bias,
                                                  const int* __restrict__ row_start,
                                                  const int* __restrict__ cnt,
                                                  const int* __restrict__ eidx,
                                                  float* __restrict__ h,
                                                  float* __restrict__ keys) {
  const int wv = (blockIdx.x * 256 + threadIdx.x) >> 6;  // wave id
  const int lane = threadIdx.x & 63;
  const int q = lane >> 4;   // node slot within wave
  const int ql = lane & 15;  // feature quarter
  const int node = wv * 4 + q;
  if (node >= NN) return;
  const int base = row_start[node];
  const int deg = cnt[node];
  float4 acc = make_float4(0.f, 0.f, 0.f, 0.f);

  for (int e0 = 0; e0 < deg; e0 += 16) {
    const int rem = deg - e0;
    const int ii = (ql < rem) ? ql : (rem - 1);
    int idx = eidx[base + e0 + ii];
#pragma unroll
    for (int j = 0; j < 16; ++j) {
      const int sj = __shfl(idx, (lane & 48) | j);
      const float wj = (j < rem) ? 1.f : 0.f;
      const float4 vj = *reinterpret_cast<const float4*>(&P[(size_t)sj * 64 + ql * 4]);
      acc.x = fmaf(wj, vj.x, acc.x);
      acc.y = fmaf(wj, vj.y, acc.y);
      acc.z = fmaf(wj, vj.z, acc.z);
      acc.w = fmaf(wj, vj.w, acc.w);
    }
  }

  const float dv = fmaxf((float)deg, 1.0f);
  float4 r4 = *reinterpret_cast<const float4*>(&R[(size_t)node * 64 + ql * 4]);
  float4 b4 = *reinterpret_cast<const float4*>(&bias[ql * 4]);
  float4 o;
  o.x = fmaxf(acc.x / dv + b4.x + r4.x, 0.f);
  o.y = fmaxf(acc.y / dv + b4.y + r4.y, 0.f);
  o.z = fmaxf(acc.z / dv + b4.z + r4.z, 0.f);
  o.w = fmaxf(acc.w / dv + b4.w + r4.w, 0.f);
  *reinterpret_cast<float4*>(&h[(size_t)node * 64 + ql * 4]) = o;
  if (keys != nullptr && ql == 15) keys[node] = o.w;  // feature 63
}

// ---- fused layer: agg_n (gather into LDS h-tile) + proj_{n+1} (GEMM) ----
// Block b owns nodes [b*128, b*128+128). Gather phase = agg v2 per quarter
// (8 nodes each), h written to LDS [128][68]. GEMM phase: h @ (WL|WR) with W
// read from global (L1 broadcast, 32KB distinct). LDS 34816B -> 4 blocks/CU.
// No global h round-trip; gather (VMEM) of one block overlaps GEMM (VALU) of
// co-resident blocks.
__global__ __launch_bounds__(256) void layer_kernel(const float* __restrict__ P,
                                                    const float* __restrict__ R,
                                                    const float* __restrict__ bias,
                                                    const int* __restrict__ row_start,
                                                    const int* __restrict__ cnt,
                                                    const int* __restrict__ eidx,
                                                    const float* __restrict__ WL,
                                                    const float* __restrict__ WR,
                                                    float* __restrict__ Pout,
                                                    float* __restrict__ Rout) {
  __shared__ float hs[128 * 68];  // 34816 B
  const int t = threadIdx.x;
  const int lane = t & 63;
  const int qd = t >> 4;   // quarter id 0..15
  const int ql = t & 15;   // feature quarter
  const int row0 = blockIdx.x * 128;

  // ---- phase A: gather (mean aggr + bias + self + relu) into LDS ----
  for (int p = 0; p < 8; ++p) {
    const int r = qd + 16 * p;
    const int node = row0 + r;
    float4 acc = make_float4(0.f, 0.f, 0.f, 0.f);
    int deg = 0;
    if (node < NN) {
      const int base = row_start[node];
      deg = cnt[node];
      for (int e0 = 0; e0 < deg; e0 += 16) {
        const int rem = deg - e0;
        const int ii = (ql < rem) ? ql : (rem - 1);
        int idx = eidx[base + e0 + ii];
#pragma unroll
        for (int j = 0; j < 16; ++j) {
          const int sj = __shfl(idx, (lane & 48) | j);
          const float wj = (j < rem) ? 1.f : 0.f;
          const float4 vj = *reinterpret_cast<const float4*>(&P[(size_t)sj * 64 + ql * 4]);
          acc.x = fmaf(wj, vj.x, acc.x);
          acc.y = fmaf(wj, vj.y, acc.y);
          acc.z = fmaf(wj, vj.z, acc.z);
          acc.w = fmaf(wj, vj.w, acc.w);
        }
      }
      const float dv = fmaxf((float)deg, 1.0f);
      float4 r4 = *reinterpret_cast<const float4*>(&R[(size_t)node * 64 + ql * 4]);
      float4 b4 = *reinterpret_cast<const float4*>(&bias[ql * 4]);
      acc.x = fmaxf(acc.x / dv + b4.x + r4.x, 0.f);
      acc.y = fmaxf(acc.y / dv + b4.y + r4.y, 0.f);
      acc.z = fmaxf(acc.z / dv + b4.z + r4.z, 0.f);
      acc.w = fmaxf(acc.w / dv + b4.w + r4.w, 0.f);
    }
    *reinterpret_cast<float4*>(&hs[r * 68 + ql * 4]) = acc;
  }
  __syncthreads();

  // ---- phase B: [128x64] @ [64x128] GEMM, 8x8 reg tile per thread ----
  const int tc = t & 15, tr = t >> 4;
  const float* WB = (tc < 8) ? WL : WR;
  const int wcolg = (tc & 7) * 8;

  float acc[8][8];
#pragma unroll
  for (int i = 0; i < 8; ++i)
#pragma unroll
    for (int j = 0; j < 8; ++j) acc[i][j] = 0.f;

  for (int kk4 = 0; kk4 < 64; kk4 += 4) {
    float4 a[8];
#pragma unroll
    for (int i = 0; i < 8; ++i)
      a[i] = *reinterpret_cast<const float4*>(&hs[(tr + 16 * i) * 68 + kk4]);
#pragma unroll
    for (int kk = 0; kk < 4; ++kk) {
      float4 b0 = *reinterpret_cast<const float4*>(&WB[(kk4 + kk) * 64 + wcolg]);
      float4 b1 = *reinterpret_cast<const float4*>(&WB[(kk4 + kk) * 64 + wcolg + 4]);
      float bv[8] = {b0.x, b0.y, b0.z, b0.w, b1.x, b1.y, b1.z, b1.w};
#pragma unroll
      for (int i = 0; i < 8; ++i) {
        float av = (kk == 0) ? a[i].x : (kk == 1) ? a[i].y : (kk == 2) ? a[i].z : a[i].w;
#pragma unroll
        for (int j = 0; j < 8; ++j) acc[i][j] = fmaf(av, bv[j], acc[i][j]);
      }
    }
  }

  float* OUT = (tc < 8) ? Pout : Rout;
  const int cb = (tc & 7) * 8;
#pragma unroll
  for (int i = 0; i < 8; ++i) {
    int row = row0 + tr + 16 * i;
    if (row < NN) {
      *reinterpret_cast<float4*>(&OUT[(size_t)row * 64 + cb]) =
          make_float4(acc[i][0], acc[i][1], acc[i][2], acc[i][3]);
      *reinterpret_cast<float4*>(&OUT[(size_t)row * 64 + cb + 4]) =
          make_float4(acc[i][4], acc[i][5], acc[i][6], acc[i][7]);
    }
  }
}

// one block (256 thr) per graph: stable top-30, conv1d, MLP head.
__global__ __launch_bounds__(256) void head_kernel(const float* __restrict__ h,
                                                   const float* __restrict__ keysArr,
                                                   const float* __restrict__ cw,
                                                   const float* __restrict__ cb,
                                                   const float* __restrict__ w1,
                                                   const float* __restrict__ bb1,
                                                   const float* __restrict__ w2,
                                                   const float* __restrict__ bb2,
                                                   float* __restrict__ out) {
  __shared__ float key[PERG];
  __shared__ int sel[KK];
  __shared__ float feat[34 * 65];
  __shared__ float cwT[192 * 33];
  __shared__ float z[896];
  __shared__ float psum[256];
  const int g = blockIdx.x;
  const int t = threadIdx.x;

  for (int idx = t; idx < 32 * 192; idx += 256) {
    int o = idx / 192, k = idx % 192;
    cwT[k * 33 + o] = cw[idx];
  }
  if (t < PERG) key[t] = keysArr[g * PERG + t];
  __syncthreads();

  if (t < PERG) {
    float kv = key[t];
    int r = 0;
    for (int m = 0; m < PERG; ++m) {
      float km = key[m];
      r += (int)((km > kv) || (km == kv && m < t));
    }
    if (r < KK) sel[r] = t;
  }
  __syncthreads();

  for (int idx = t; idx < KK * HH; idx += 256) {
    int r = idx >> 6, f = idx & 63;
    feat[r * 65 + f] = h[(size_t)(g * PERG + sel[r]) * HH + f];
  }
  __syncthreads();

  {
    const int o = t & 31;
    const int pg = t >> 5;
    float zacc[4] = {0.f, 0.f, 0.f, 0.f};
    int i = 0, tt = 0;
    for (int k = 0; k < 192; ++k) {
      float c = cwT[k * 33 + o];
#pragma unroll
      for (int j = 0; j < 4; ++j) {
        int p = pg + 8 * j;
        zacc[j] = fmaf(c, feat[(p + tt) * 65 + i], zacc[j]);
      }
      if (++tt == 3) {
        tt = 0;
        ++i;
      }
    }
    float cbo = cb[o];
#pragma unroll
    for (int j = 0; j < 4; ++j) {
      int p = pg + 8 * j;
      if (p < 28) z[o * 28 + p] = fmaxf(zacc[j] + cbo, 0.f);
    }
  }
  __syncthreads();

  {
    const int hh = t & 63;
    const int quarter = t >> 6;
    const int q0 = quarter * 224;
    float acc = 0.f;
    for (int q = 0; q < 224; ++q)
      acc = fmaf(z[q0 + q], w1[(size_t)(q0 + q) * 64 + hh], acc);
    psum[t] = acc;
  }
  __syncthreads();

  if (t < 64) {
    float o1 = fmaxf(bb1[t] + psum[t] + psum[t + 64] + psum[t + 128] + psum[t + 192], 0.f);
    float v = o1 * w2[t];
#pragma unroll
    for (int off = 32; off > 0; off >>= 1) v += __shfl_down(v, off);
    if (t == 0) out[g] = v + bb2[0];
  }
}

extern "C" void kernel_launch(void* const* d_in, const int* in_sizes, int n_in,
                              void* d_out, int out_size, void* d_ws, size_t ws_size,
                              hipStream_t stream) {
  const float* x = (const float*)d_in[0];
  const int* src = (const int*)d_in[1];
  const int* dst = (const int*)d_in[2];
  const float* wl1 = (const float*)d_in[4];
  const float* wr1 = (const float*)d_in[5];
  const float* b1 = (const float*)d_in[6];
  const float* wl2 = (const float*)d_in[7];
  const float* wr2 = (const float*)d_in[8];
  const float* b2 = (const float*)d_in[9];
  const float* wl3 = (const float*)d_in[10];
  const float* wr3 = (const float*)d_in[11];
  const float* b3 = (const float*)d_in[12];
  const float* cw = (const float*)d_in[13];
  const float* cb = (const float*)d_in[14];
  const float* w1 = (const float*)d_in[15];
  const float* bb1 = (const float*)d_in[16];
  const float* w2 = (const float*)d_in[17];
  const float* bb2 = (const float*)d_in[18];
  float* out = (float*)d_out;

  char* w = (char*)d_ws;
  size_t used = 0;
  auto carve = [&](size_t bytes) {
    char* p = w;
    size_t pad = (bytes + 255) & ~(size_t)255;
    w += pad;
    used += pad;
    return p;
  };
  int* row_start = (int*)carve((size_t)NN * 4);
  int* cnt = (int*)carve((size_t)NN * 4);
  int* eidx = (int*)carve((size_t)EE * 4);
  float* P = (float*)carve((size_t)NN * 64 * 4);
  float* R = (float*)carve((size_t)NN * 64 * 4);
  float* hbuf = (float*)carve((size_t)NN * 64 * 4);
  float* keys = (float*)carve((size_t)NN * 4);
  int* gcur = (int*)carve((size_t)NB * 4);
  size_t used_base = used;
  float* R2 = (float*)carve((size_t)NN * 64 * 4);  // extra buffer for fused path
  // pairs aliases hbuf; csr reads pairs before anything writes hbuf. In the
  // fused path, hbuf doubles as P2 (layer1 output), written after csr.
  int* pairs = (int*)hbuf;
  float* P2 = hbuf;

  const bool fused_layers = (used <= ws_size);

  hipMemsetAsync(gcur, 0, (size_t)NB * 4, stream);
  fused_bucket_proj<<<BUCKET_BLOCKS + PROJ_BLOCKS, 256, 0, stream>>>(
      src, dst, gcur, pairs, x, wl1, wr1, P, R);
  csr_kernel<<<NB, 256, 0, stream>>>(gcur, pairs, row_start, cnt, eidx);

  const int aggGrid = (NN + 15) / 16;
  if (fused_layers) {
    // layer1: agg(P,R,b1) -> h1 (LDS) -> P2,R2 = h1 @ (wl2|wr2)
    layer_kernel<<<LAYER_BLOCKS, 256, 0, stream>>>(P, R, b1, row_start, cnt, eidx,
                                                   wl2, wr2, P2, R2);
    // layer2: agg(P2,R2,b2) -> h2 (LDS) -> P,R = h2 @ (wl3|wr3)
    layer_kernel<<<LAYER_BLOCKS, 256, 0, stream>>>(P2, R2, b2, row_start, cnt, eidx,
                                                   wl3, wr3, P, R);
    // final agg -> h3 global + keys (hbuf free again: P2 fully consumed)
    agg_kernel<<<aggGrid, 256, 0, stream>>>(P, R, b3, row_start, cnt, eidx, hbuf, keys);
  } else {
    (void)used_base;
    agg_kernel<<<aggGrid, 256, 0, stream>>>(P, R, b1, row_start, cnt, eidx, hbuf, nullptr);
    proj_kernel<64><<<PROJ_BLOCKS, 256, 0, stream>>>(hbuf, wl2, wr2, P, R);
    agg_kernel<<<aggGrid, 256, 0, stream>>>(P, R, b2, row_start, cnt, eidx, hbuf, nullptr);
    proj_kernel<64><<<PROJ_BLOCKS, 256, 0, stream>>>(hbuf, wl3, wr3, P, R);
    agg_kernel<<<aggGrid, 256, 0, stream>>>(P, R, b3, row_start, cnt, eidx, hbuf, keys);
  }
  head_kernel<<<GG, 256, 0, stream>>>(hbuf, keys, cw, cb, w1, bb1, w2, bb2, out);
}